// Round 11
// baseline (554.272 us; speedup 1.0000x reference)
//
#include <hip/hip_runtime.h>
#include <stdint.h>

#define HD 2048
#define FD 1024
#define NE 16
#define NPAIR 8192
#define BM 256
#define MAXT 48

typedef short bf16x8 __attribute__((ext_vector_type(8)));
typedef float f32x4 __attribute__((ext_vector_type(4)));
typedef unsigned short u16;

static __device__ __forceinline__ u16 f2bf(float f) {
  uint32_t u = __float_as_uint(f);
  u += 0x7FFFu + ((u >> 16) & 1u);
  return (u16)(u >> 16);
}

// Counted barriers (T4): drain the 8 glds A-loads + all LDS ops, leave the
// newest N vmem ops (next-next-stage B prefetch) in flight across the barrier.
// N=5: inflated path (4 int4 + 1 scale). N=2: packed path (1 uint4 + 1 scale).
static __device__ __forceinline__ void sbar_cnt5() {
  __builtin_amdgcn_sched_barrier(0);
  asm volatile("s_waitcnt vmcnt(5) lgkmcnt(0)" ::: "memory");
  __builtin_amdgcn_s_barrier();
  __builtin_amdgcn_sched_barrier(0);
}
static __device__ __forceinline__ void sbar_cnt2() {
  __builtin_amdgcn_sched_barrier(0);
  asm volatile("s_waitcnt vmcnt(2) lgkmcnt(0)" ::: "memory");
  __builtin_amdgcn_s_barrier();
  __builtin_amdgcn_sched_barrier(0);
}
static __device__ __forceinline__ void sbar_all() {
  __builtin_amdgcn_sched_barrier(0);
  asm volatile("s_waitcnt vmcnt(0) lgkmcnt(0)" ::: "memory");
  __builtin_amdgcn_s_barrier();
  __builtin_amdgcn_sched_barrier(0);
}

// Scale-folded byte tables for e2m1 -> bf16 dequant via v_perm.
struct DqTab { uint32_t hA, hB, lA, lB; };

static __device__ __forceinline__ DqTab make_tab(uint32_t sbits) {
  int n = (int)(sbits >> 23) - 127;
  int q = n >> 1;
  uint32_t r = (uint32_t)(n & 1);
  uint32_t mq = (uint32_t)(-q);
  uint32_t sub1 = mq * 0x01010100u;  // entry 0 (zero) untouched
  uint32_t subA = mq * 0x01010101u;
  DqTab t;
  t.hA = (r ? 0x40403F00u : 0x3F3F3F00u) - sub1;
  t.hB = (r ? 0x41414040u : 0x40404040u) - subA;
  t.lA = r ? 0x40008000u : 0xC0800000u;
  t.lB = r ? 0x4000C080u : 0xC0804000u;
  return t;
}

// p: 4 packed fp4 bytes (8 values, low nibble first) -> 4 dwords of bf16 pairs
static __device__ __forceinline__ void dq8(uint32_t p, const DqTab& t, uint32_t* d) {
  uint32_t a = p & 0x0F0F0F0Fu;
  uint32_t b = (p >> 4) & 0x0F0F0F0Fu;
  uint32_t x0 = __builtin_amdgcn_perm(b, a, 0x05010400u);
  uint32_t x1 = __builtin_amdgcn_perm(b, a, 0x07030602u);
  uint32_t m0 = x0 & 0x07070707u;
  uint32_t m1 = x1 & 0x07070707u;
  uint32_t h0 = __builtin_amdgcn_perm(t.hB, t.hA, m0) | ((x0 & 0x08080808u) << 4);
  uint32_t h1 = __builtin_amdgcn_perm(t.hB, t.hA, m1) | ((x1 & 0x08080808u) << 4);
  uint32_t l0 = __builtin_amdgcn_perm(t.lB, t.lA, m0);
  uint32_t l1 = __builtin_amdgcn_perm(t.lB, t.lA, m1);
  d[0] = __builtin_amdgcn_perm(h0, l0, 0x05010400u);
  d[1] = __builtin_amdgcn_perm(h0, l0, 0x07030602u);
  d[2] = __builtin_amdgcn_perm(h1, l1, 0x05010400u);
  d[3] = __builtin_amdgcn_perm(h1, l1, 0x07030602u);
}

static __device__ __forceinline__ uint32_t pack4(int4 v) {
  return (uint32_t)(v.x & 0xFF) | ((uint32_t)(v.y & 0xFF) << 8) |
         ((uint32_t)(v.z & 0xFF) << 16) | ((uint32_t)v.w << 24);
}

// One MFMA B-fragment (8 bf16) from packed LDS (8 u32/row + 1 pad) + scales (2/row).
static __device__ __forceinline__ bf16x8 dqfrag(const uint32_t* pB, const uint32_t* pS,
                                                int row, int j, int q) {
  uint32_t pb = pB[row * 9 + j * 4 + q];
  DqTab t = make_tab(pS[row * 2 + j]);
  uint32_t d[4];
  dq8(pb, t, d);
  union { uint32_t u[4]; bf16x8 v; } cv;
  cv.u[0] = d[0]; cv.u[1] = d[1]; cv.u[2] = d[2]; cv.u[3] = d[3];
  return cv.v;
}

// Direct global->LDS, 16B per lane; dest = wave-uniform base + lane*16.
static __device__ __forceinline__ void glds16(const void* g, void* l) {
  __builtin_amdgcn_global_load_lds(
      (const __attribute__((address_space(1))) uint32_t*)g,
      (__attribute__((address_space(3))) uint32_t*)l, 16, 0, 0);
}

__global__ void cast_kernel(const float* __restrict__ x, u16* __restrict__ xb) {
  int i = blockIdx.x * 256 + threadIdx.x;
  float4 v = ((const float4*)x)[i];
  ushort4 o;
  o.x = f2bf(v.x); o.y = f2bf(v.y); o.z = f2bf(v.z); o.w = f2bf(v.w);
  ((ushort4*)xb)[i] = o;
}

__global__ void zero_kernel(float4* __restrict__ out) {
  out[blockIdx.x * 256 + threadIdx.x] = float4{0.f, 0.f, 0.f, 0.f};
}

// One-time weight repack: int32-per-byte (4x inflated) -> true packed bytes.
// Fully coalesced stream; leaves packed arrays L3-resident.
// gup: 8,388,608 int4s -> u32; dwn: 4,194,304. grid = 49152 x 256.
__global__ void repack_kernel(const int* __restrict__ g, const int* __restrict__ d,
                              uint32_t* __restrict__ gp, uint32_t* __restrict__ dp) {
  int i = blockIdx.x * 256 + threadIdx.x;
  if (i < 8388608) {
    int4 v = ((const int4*)g)[i];
    gp[i] = pack4(v);
  } else {
    int j = i - 8388608;
    int4 v = ((const int4*)d)[j];
    dp[j] = pack4(v);
  }
}

__global__ void route_kernel(const int* __restrict__ ids, const float* __restrict__ tw,
                             int* __restrict__ rows, float* __restrict__ rw,
                             int* __restrict__ te) {
  __shared__ int cnt[NE], base[NE], run[NE];
  int tid = threadIdx.x;
  if (tid < NE) { cnt[tid] = 0; run[tid] = 0; }
  __syncthreads();
  for (int i = tid; i < NPAIR; i += 256) atomicAdd(&cnt[ids[i]], 1);
  __syncthreads();
  if (tid == 0) {
    int cum = 0;
    for (int e = 0; e < NE; ++e) {
      base[e] = cum;
      int nt = (cnt[e] + BM - 1) >> 8;
      for (int j = 0; j < nt; ++j) te[(cum >> 8) + j] = e;
      cum += nt << 8;
    }
    for (int t = cum >> 8; t < MAXT; ++t) te[t] = -1;
  }
  __syncthreads();
  for (int i = tid; i < MAXT * BM; i += 256) { rows[i] = -1; rw[i] = 0.f; }
  __syncthreads();
  for (int i = tid; i < NPAIR; i += 256) {
    int e = ids[i];
    int p = base[e] + atomicAdd(&run[e], 1);
    rows[p] = i >> 2;
    rw[p] = tw[i];
  }
}

// gate_up GEMM + SwiGLU + routing weight -> act (bf16). BM=256, BN=64+64.
// Stage K:64, dbuf, ONE counted barrier per stage; A via global_load_lds
// (pre-swizzled src, XOR-swizzled reads); B packed LDS, dequant on read;
// 2Mx2N wave decomposition. PK=true: B from repacked array (1/4 bytes, 1 uint4
// load/thread/stage, vmcnt(2)); PK=false: inflated int32 path (vmcnt(5)).
template <bool PK>
__global__ __launch_bounds__(256, 2) void gemm1_t(
    const u16* __restrict__ xb, const int* __restrict__ gup32,
    const uint32_t* __restrict__ gpk, const uint32_t* __restrict__ gus,
    const int* __restrict__ rows, const float* __restrict__ rw,
    const int* __restrict__ te, u16* __restrict__ act) {
  const int tile = blockIdx.y;
  const int e = te[tile];
  if (e < 0) return;
  const int f0 = blockIdx.x * 64;

  __shared__ u16 sA[2][BM * 64];         // 64 KB: [row][64el], swizzled content
  __shared__ uint32_t sBp[2][128 * 9];   // 9.2 KB packed fp4
  __shared__ uint32_t sSc[2][256];       // 2 KB scales (2 per row)
  __shared__ int rows_s[BM];
  __shared__ float rw_s[BM];

  const int tid = threadIdx.x;
  rows_s[tid] = rows[tile * BM + tid];
  rw_s[tid] = rw[tile * BM + tid];
  __syncthreads();

  const int lane = tid & 63;
  const int w = tid >> 6;
  const int wr = w >> 1;   // 0..1 M-half (128 rows)
  const int wc = w & 1;    // 0..1 N-half (32 gate + 32 up cols)
  const int q = lane >> 4, c = lane & 15;

  // A glds staging: wave w stages LDS rows w*64..w*64+63.
  uint32_t aofs[8];
#pragma unroll
  for (int i = 0; i < 8; ++i) {
    const int lrow = w * 64 + i * 8 + (lane >> 3);
    int grow = rows_s[lrow];
    grow = grow < 0 ? 0 : grow;
    aofs[i] = (uint32_t)grow * HD + (uint32_t)(((lane & 7) ^ (lrow & 7)) << 3);
  }

  // B staging maps.
  uint32_t obj[4];   // inflated: 4 rows x 16B-of-128B window
  uint32_t pkb = 0;  // packed: word base for row (tid>>1), half (tid&1)
  int pr = 0, ph = 0;
  if constexpr (PK) {
    pr = tid >> 1; ph = tid & 1;
    const int o_ = pr < 64 ? f0 + pr : 1024 + f0 + (pr - 64);
    pkb = (uint32_t)(e * 2048 + o_) * 256 + (uint32_t)(ph * 4);
  } else {
#pragma unroll
    for (int j = 0; j < 4; ++j) {
      const int r_ = (tid >> 3) + j * 32;
      const int o_ = r_ < 64 ? f0 + r_ : 1024 + f0 + (r_ - 64);
      obj[j] = (uint32_t)(e * 2048 + o_) * 1024 + (uint32_t)((tid & 7) << 2);
    }
  }
  const int r_sc = tid >> 1;
  const int o_sc = r_sc < 64 ? f0 + r_sc : 1024 + f0 + (r_sc - 64);
  const uint32_t scb = (uint32_t)(e * 2048 + o_sc) * 64 + (uint32_t)(tid & 1);

  // swizzled in-row read offsets (u16 units) for K-step j=0/1
  const int x0 = ((q * 16) ^ ((c & 7) << 4)) >> 1;
  const int x1 = ((64 + q * 16) ^ ((c & 7) << 4)) >> 1;

  f32x4 Cg[8][2], Cu[8][2];
#pragma unroll
  for (int s = 0; s < 8; ++s)
#pragma unroll
    for (int t2 = 0; t2 < 2; ++t2) {
      Cg[s][t2] = f32x4{0.f, 0.f, 0.f, 0.f};
      Cu[s][t2] = f32x4{0.f, 0.f, 0.f, 0.f};
    }

  int4 breg[4];
  uint4 bpk;
  uint32_t sreg;

  // prologue: A(0) glds -> buf0; B(0) -> LDS buf0; B(1) -> regs. Full drain once.
  {
#pragma unroll
    for (int i = 0; i < 8; ++i)
      glds16(xb + aofs[i], &sA[0][(w * 64 + i * 8) * 64]);
    if constexpr (PK) {
      uint4 b0 = *(const uint4*)(gpk + pkb);
      sBp[0][pr * 9 + ph * 4 + 0] = b0.x;
      sBp[0][pr * 9 + ph * 4 + 1] = b0.y;
      sBp[0][pr * 9 + ph * 4 + 2] = b0.z;
      sBp[0][pr * 9 + ph * 4 + 3] = b0.w;
      sSc[0][tid] = gus[scb];
      bpk = *(const uint4*)(gpk + pkb + 8);
      sreg = gus[scb + 2];
    } else {
      int4 b0[4];
#pragma unroll
      for (int j = 0; j < 4; ++j) b0[j] = *(const int4*)(gup32 + obj[j]);
      uint32_t s0 = gus[scb];
#pragma unroll
      for (int j = 0; j < 4; ++j)
        sBp[0][((tid >> 3) + j * 32) * 9 + (tid & 7)] = pack4(b0[j]);
      sSc[0][tid] = s0;
#pragma unroll
      for (int j = 0; j < 4; ++j) breg[j] = *(const int4*)(gup32 + obj[j] + 32);
      sreg = gus[scb + 2];
    }
    sbar_all();
  }

  for (int s = 0; s < 32; ++s) {
    const int cur = s & 1;
    // [oldest vmem this stage] A glds for s+1, + B ds_write (regs from s-1 issue)
    if (s < 31) {
#pragma unroll
      for (int i = 0; i < 8; ++i)
        glds16(xb + aofs[i] + (uint32_t)(s + 1) * 64, &sA[cur ^ 1][(w * 64 + i * 8) * 64]);
      if constexpr (PK) {
        sBp[cur ^ 1][pr * 9 + ph * 4 + 0] = bpk.x;
        sBp[cur ^ 1][pr * 9 + ph * 4 + 1] = bpk.y;
        sBp[cur ^ 1][pr * 9 + ph * 4 + 2] = bpk.z;
        sBp[cur ^ 1][pr * 9 + ph * 4 + 3] = bpk.w;
      } else {
#pragma unroll
        for (int j = 0; j < 4; ++j)
          sBp[cur ^ 1][((tid >> 3) + j * 32) * 9 + (tid & 7)] = pack4(breg[j]);
      }
      sSc[cur ^ 1][tid] = sreg;
    }
    // pin: glds must be OLDER than the B issue below (vmcnt counting relies on it)
    __builtin_amdgcn_sched_barrier(0);
    // [newest vmem this stage] B loads for s+2 — stay in flight across the barrier
    if (s < 30) {
      if constexpr (PK) {
        bpk = *(const uint4*)(gpk + pkb + (uint32_t)(s + 2) * 8);
      } else {
#pragma unroll
        for (int j = 0; j < 4; ++j)
          breg[j] = *(const int4*)(gup32 + obj[j] + (uint32_t)(s + 2) * 32);
      }
      sreg = gus[scb + (uint32_t)(s + 2) * 2];
    }
    // compute stage s: LDS-only ops
#pragma unroll
    for (int j = 0; j < 2; ++j) {
      const int xo = j ? x1 : x0;
      bf16x8 bg[2], bu[2];
#pragma unroll
      for (int t2 = 0; t2 < 2; ++t2) {
        bg[t2] = dqfrag(sBp[cur], sSc[cur], wc * 32 + t2 * 16 + c, j, q);
        bu[t2] = dqfrag(sBp[cur], sSc[cur], 64 + wc * 32 + t2 * 16 + c, j, q);
      }
#pragma unroll
      for (int s4 = 0; s4 < 8; ++s4) {
        bf16x8 af = *(const bf16x8*)&sA[cur][(wr * 128 + s4 * 16 + c) * 64 + xo];
#pragma unroll
        for (int t2 = 0; t2 < 2; ++t2) {
          Cg[s4][t2] = __builtin_amdgcn_mfma_f32_16x16x32_bf16(af, bg[t2], Cg[s4][t2], 0, 0, 0);
          Cu[s4][t2] = __builtin_amdgcn_mfma_f32_16x16x32_bf16(af, bu[t2], Cu[s4][t2], 0, 0, 0);
        }
      }
    }
    // counted barrier while B(s+2) prefetch stays in flight; tail stages drain all
    if (s < 30) { if constexpr (PK) sbar_cnt2(); else sbar_cnt5(); }
    else sbar_all();
  }

#pragma unroll
  for (int s4 = 0; s4 < 8; ++s4) {
    const int mlb = wr * 128 + s4 * 16 + q * 4;
#pragma unroll
    for (int t2 = 0; t2 < 2; ++t2) {
      const int fg = f0 + wc * 32 + t2 * 16 + c;
#pragma unroll
      for (int r = 0; r < 4; ++r) {
        const int ml = mlb + r;
        float g = Cg[s4][t2][r];
        float u = Cu[s4][t2][r];
        float aval = g / (1.f + __expf(-g)) * u * rw_s[ml];
        act[(size_t)(tile * BM + ml) * FD + fg] = f2bf(aval);
      }
    }
  }
}

// down GEMM. BM=256, BN=128. Same counted-barrier structure; 2Mx2N waves.
template <bool PK>
__global__ __launch_bounds__(256, 2) void gemm2_t(
    const u16* __restrict__ act, const int* __restrict__ dwn32,
    const uint32_t* __restrict__ dpk, const uint32_t* __restrict__ dsc,
    const int* __restrict__ rows, const int* __restrict__ te,
    float* __restrict__ out) {
  const int tile = blockIdx.y;
  const int e = te[tile];
  if (e < 0) return;
  const int h0 = blockIdx.x * 128;

  __shared__ u16 sA[2][BM * 64];
  __shared__ uint32_t sBp[2][128 * 9];
  __shared__ uint32_t sSc[2][256];
  __shared__ int rows_s[BM];

  const int tid = threadIdx.x;
  rows_s[tid] = rows[tile * BM + tid];
  __syncthreads();

  const int lane = tid & 63;
  const int w = tid >> 6;
  const int wr = w >> 1;   // 0..1
  const int wc = w & 1;    // 0..1
  const int q = lane >> 4, c = lane & 15;

  uint32_t aofs[8];
#pragma unroll
  for (int i = 0; i < 8; ++i) {
    const int lrow = w * 64 + i * 8 + (lane >> 3);
    aofs[i] = (uint32_t)(tile * BM + lrow) * FD + (uint32_t)(((lane & 7) ^ (lrow & 7)) << 3);
  }

  uint32_t obj[4];
  uint32_t pkb = 0;
  int pr = 0, ph = 0;
  if constexpr (PK) {
    pr = tid >> 1; ph = tid & 1;
    pkb = (uint32_t)(e * 2048 + h0 + pr) * 128 + (uint32_t)(ph * 4);
  } else {
#pragma unroll
    for (int j = 0; j < 4; ++j) {
      const int r_ = (tid >> 3) + j * 32;
      obj[j] = (uint32_t)(e * 2048 + h0 + r_) * 512 + (uint32_t)((tid & 7) << 2);
    }
  }
  const uint32_t scb = (uint32_t)(e * 2048 + h0 + (tid >> 1)) * 32 + (uint32_t)(tid & 1);

  const int x0 = ((q * 16) ^ ((c & 7) << 4)) >> 1;
  const int x1 = ((64 + q * 16) ^ ((c & 7) << 4)) >> 1;

  f32x4 Cd[8][4];
#pragma unroll
  for (int s = 0; s < 8; ++s)
#pragma unroll
    for (int t2 = 0; t2 < 4; ++t2) Cd[s][t2] = f32x4{0.f, 0.f, 0.f, 0.f};

  int4 breg[4];
  uint4 bpk;
  uint32_t sreg;

  {
#pragma unroll
    for (int i = 0; i < 8; ++i)
      glds16(act + aofs[i], &sA[0][(w * 64 + i * 8) * 64]);
    if constexpr (PK) {
      uint4 b0 = *(const uint4*)(dpk + pkb);
      sBp[0][pr * 9 + ph * 4 + 0] = b0.x;
      sBp[0][pr * 9 + ph * 4 + 1] = b0.y;
      sBp[0][pr * 9 + ph * 4 + 2] = b0.z;
      sBp[0][pr * 9 + ph * 4 + 3] = b0.w;
      sSc[0][tid] = dsc[scb];
      bpk = *(const uint4*)(dpk + pkb + 8);
      sreg = dsc[scb + 2];
    } else {
      int4 b0[4];
#pragma unroll
      for (int j = 0; j < 4; ++j) b0[j] = *(const int4*)(dwn32 + obj[j]);
      uint32_t s0 = dsc[scb];
#pragma unroll
      for (int j = 0; j < 4; ++j)
        sBp[0][((tid >> 3) + j * 32) * 9 + (tid & 7)] = pack4(b0[j]);
      sSc[0][tid] = s0;
#pragma unroll
      for (int j = 0; j < 4; ++j) breg[j] = *(const int4*)(dwn32 + obj[j] + 32);
      sreg = dsc[scb + 2];
    }
    sbar_all();
  }

  for (int s = 0; s < 16; ++s) {
    const int cur = s & 1;
    if (s < 15) {
#pragma unroll
      for (int i = 0; i < 8; ++i)
        glds16(act + aofs[i] + (uint32_t)(s + 1) * 64, &sA[cur ^ 1][(w * 64 + i * 8) * 64]);
      if constexpr (PK) {
        sBp[cur ^ 1][pr * 9 + ph * 4 + 0] = bpk.x;
        sBp[cur ^ 1][pr * 9 + ph * 4 + 1] = bpk.y;
        sBp[cur ^ 1][pr * 9 + ph * 4 + 2] = bpk.z;
        sBp[cur ^ 1][pr * 9 + ph * 4 + 3] = bpk.w;
      } else {
#pragma unroll
        for (int j = 0; j < 4; ++j)
          sBp[cur ^ 1][((tid >> 3) + j * 32) * 9 + (tid & 7)] = pack4(breg[j]);
      }
      sSc[cur ^ 1][tid] = sreg;
    }
    __builtin_amdgcn_sched_barrier(0);
    if (s < 14) {
      if constexpr (PK) {
        bpk = *(const uint4*)(dpk + pkb + (uint32_t)(s + 2) * 8);
      } else {
#pragma unroll
        for (int j = 0; j < 4; ++j)
          breg[j] = *(const int4*)(dwn32 + obj[j] + (uint32_t)(s + 2) * 32);
      }
      sreg = dsc[scb + (uint32_t)(s + 2) * 2];
    }
#pragma unroll
    for (int j = 0; j < 2; ++j) {
      const int xo = j ? x1 : x0;
      bf16x8 bf_[4];
#pragma unroll
      for (int t2 = 0; t2 < 4; ++t2)
        bf_[t2] = dqfrag(sBp[cur], sSc[cur], wc * 64 + t2 * 16 + c, j, q);
#pragma unroll
      for (int s4 = 0; s4 < 8; ++s4) {
        bf16x8 af = *(const bf16x8*)&sA[cur][(wr * 128 + s4 * 16 + c) * 64 + xo];
#pragma unroll
        for (int t2 = 0; t2 < 4; ++t2)
          Cd[s4][t2] = __builtin_amdgcn_mfma_f32_16x16x32_bf16(af, bf_[t2], Cd[s4][t2], 0, 0, 0);
      }
    }
    if (s < 14) { if constexpr (PK) sbar_cnt2(); else sbar_cnt5(); }
    else sbar_all();
  }

#pragma unroll
  for (int s4 = 0; s4 < 8; ++s4) {
    const int mlb = wr * 128 + s4 * 16 + q * 4;
#pragma unroll
    for (int t2 = 0; t2 < 4; ++t2) {
      const int hg = h0 + wc * 64 + t2 * 16 + c;
#pragma unroll
      for (int r = 0; r < 4; ++r) {
        int token = rows_s[mlb + r];
        if (token >= 0) atomicAdd(&out[(size_t)token * HD + hg], Cd[s4][t2][r]);
      }
    }
  }
}

extern "C" void kernel_launch(void* const* d_in, const int* in_sizes, int n_in,
                              void* d_out, int out_size, void* d_ws, size_t ws_size,
                              hipStream_t stream) {
  const float* hidden = (const float*)d_in[0];
  const float* tw = (const float*)d_in[1];
  const int* ids = (const int*)d_in[2];
  const int* gup32 = (const int*)d_in[3];        // uint8 packed bytes, uploaded as int32
  const uint32_t* gus = (const uint32_t*)d_in[4];
  const int* dwn32 = (const int*)d_in[5];
  const uint32_t* dsc = (const uint32_t*)d_in[6];
  float* out = (float*)d_out;

  char* ws = (char*)d_ws;
  int* rows = (int*)(ws);                    // 48 KB
  float* rw = (float*)(ws + 49152);          // 48 KB
  int* te = (int*)(ws + 98304);              // 192 B
  u16* xb = (u16*)(ws + 131072);             // 8 MB
  u16* act = (u16*)(ws + 8519680);           // 25.2 MB, ends 33685504

  // Repacked weight region (runtime-gated on workspace size):
  const size_t GPK_OFF = 33685504ULL;                    // 33.5 MB gup packed
  const size_t DPK_OFF = GPK_OFF + 33554432ULL;          // 16.8 MB dwn packed
  const size_t WS_PK = DPK_OFF + 16777216ULL;            // = 84,017,152
  const bool pk = ws_size >= WS_PK;
  uint32_t* gpk = (uint32_t*)(ws + GPK_OFF);
  uint32_t* dpk = (uint32_t*)(ws + DPK_OFF);

  cast_kernel<<<dim3(4096), dim3(256), 0, stream>>>(hidden, xb);
  zero_kernel<<<dim3(4096), dim3(256), 0, stream>>>((float4*)out);
  route_kernel<<<dim3(1), dim3(256), 0, stream>>>(ids, tw, rows, rw, te);
  if (pk) {
    repack_kernel<<<dim3(49152), dim3(256), 0, stream>>>(gup32, dwn32, gpk, dpk);
    gemm1_t<true><<<dim3(16, MAXT), dim3(256), 0, stream>>>(xb, gup32, gpk, gus, rows, rw, te, act);
    gemm2_t<true><<<dim3(16, MAXT), dim3(256), 0, stream>>>(act, dwn32, dpk, dsc, rows, te, out);
  } else {
    gemm1_t<false><<<dim3(16, MAXT), dim3(256), 0, stream>>>(xb, gup32, gpk, gus, rows, rw, te, act);
    gemm2_t<false><<<dim3(16, MAXT), dim3(256), 0, stream>>>(act, dwn32, dpk, dsc, rows, te, out);
  }
}